// Round 4
// baseline (445.962 us; speedup 1.0000x reference)
//
#include <hip/hip_runtime.h>

#define NH 32   // S-box hidden width

// d_ws float layout: [0,256) = w1t (w1 transposed, [h][k]);
//                    [256,1664) = t0 = w01*rk + xb0  ([11][128]);
//                    [1664,3072) = t1 = w11*rk + xb1  ([11][128]).
#define WS_W1T 0
#define WS_T0  256
#define WS_T1  1664

__global__ __launch_bounds__(256) void prep_kernel(
    const float* __restrict__ rk,   // [11*128]
    const float* __restrict__ xw,   // [4]
    const float* __restrict__ xb,   // [2]
    const float* __restrict__ w1,   // [8][32]
    float* __restrict__ ws)
{
    const int idx = blockIdx.x * 256 + threadIdx.x;
    const float w01 = xw[1], w11 = xw[3], xb0 = xb[0], xb1 = xb[1];
    if (idx < NH * 8) {
        int h = idx >> 3, k = idx & 7;
        ws[WS_W1T + idx] = w1[k * NH + h];
    }
    if (idx < 11 * 128) {
        float kv = rk[idx];
        ws[WS_T0 + idx] = fmaf(w01, kv, xb0);
        ws[WS_T1 + idx] = fmaf(w11, kv, xb1);
    }
}

// XOR-of-3 parity gadget: relu(s) - 2relu(s-1) + 2relu(s-2) - 2relu(s-3)
__device__ __forceinline__ float mixg(float s) {
    float t0 = fmaxf(s, 0.f);
    float t1 = fmaxf(s - 1.f, 0.f);
    float t2 = fmaxf(s - 2.f, 0.f);
    float t3 = fmaxf(s - 3.f, 0.f);
    return t0 - 2.f * (t1 - t2 + t3);
}

// SubBytes on 8 of the 16 bytes (columns J0, J0+1). Weights come from GLOBAL
// memory with wave-uniform indices -> scalar loads (s_load_dwordx8) into
// SGPRs; the FMA stream is v_fma_f32 v,s,v,v with no marshalling movs.
// All st indices are compile-time so st stays in VGPRs.
template<int J0>
__device__ __forceinline__ void sub_group(float (&st)[4][4][8],
                                          const float* __restrict__ w0g,
                                          const float* __restrict__ b0g,
                                          const float* __restrict__ w1tg)
{
    float acc[4][2][8];
    #pragma unroll
    for (int i = 0; i < 4; ++i)
        #pragma unroll
        for (int jj = 0; jj < 2; ++jj)
            #pragma unroll
            for (int k = 0; k < 8; ++k) acc[i][jj][k] = 0.f;

    #pragma unroll 2
    for (int h = 0; h < NH; ++h) {
        const float* __restrict__ wr = w0g + h * 8;   // uniform -> SGPR
        const float* __restrict__ vr = w1tg + h * 8;  // uniform -> SGPR
        const float bb = b0g[h];                      // uniform -> SGPR
        #pragma unroll
        for (int i = 0; i < 4; ++i) {
            #pragma unroll
            for (int jj = 0; jj < 2; ++jj) {
                float hv = bb;
                #pragma unroll
                for (int k = 0; k < 8; ++k) hv = fmaf(wr[k], st[i][J0 + jj][k], hv);
                hv = fmaxf(hv, 0.f);
                #pragma unroll
                for (int k = 0; k < 8; ++k) acc[i][jj][k] = fmaf(vr[k], hv, acc[i][jj][k]);
            }
        }
    }
    #pragma unroll
    for (int i = 0; i < 4; ++i)
        #pragma unroll
        for (int jj = 0; jj < 2; ++jj)
            #pragma unroll
            for (int k = 0; k < 8; ++k) st[i][J0 + jj][k] = acc[i][jj][k];
}

__global__ __attribute__((amdgpu_flat_work_group_size(256, 256),
                          amdgpu_waves_per_eu(2, 2)))
void neural_aes_kernel(
    const float* __restrict__ st_in,   // [B,128]
    const float* __restrict__ xw,      // [2,2]
    const float* __restrict__ w0g,     // [32,8]
    const float* __restrict__ b0g,     // [32]
    const float* __restrict__ wsg,     // w1t + t0 + t1 (prepped)
    float* __restrict__ out, int B)
{
    const float w00 = xw[0], w10 = xw[2];
    const float* __restrict__ w1tg = wsg + WS_W1T;
    const float* __restrict__ t0g  = wsg + WS_T0;
    const float* __restrict__ t1g  = wsg + WS_T1;

    const int b = blockIdx.x * 256 + threadIdx.x;
    if (b >= B) return;
    const float* __restrict__ inp = st_in + (size_t)b * 128;
    float* __restrict__ op = out + (size_t)b * 128;

    // st[i][j][k] = input[j*32 + i*8 + k]  (reshape(4,4,8).swapaxes(1,2))
    float st[4][4][8];

    // Load + initial ARK (round key 0); t0g/t1g reads are uniform -> SGPR
    #pragma unroll
    for (int j = 0; j < 4; ++j) {
        #pragma unroll
        for (int i = 0; i < 4; ++i) {
            float4 a = *(const float4*)(inp + j * 32 + i * 8);
            float4 c = *(const float4*)(inp + j * 32 + i * 8 + 4);
            float xv[8] = {a.x, a.y, a.z, a.w, c.x, c.y, c.z, c.w};
            #pragma unroll
            for (int k = 0; k < 8; ++k) {
                float c0 = fmaf(w00, xv[k], t0g[i * 32 + j * 8 + k]);
                float c1 = fmaf(w10, xv[k], t1g[i * 32 + j * 8 + k]);
                st[i][j][k] = fmaxf(c0, 0.f) + fmaxf(c1, 0.f);
            }
        }
    }

    // Rounds 1..9: SubBytes, ShiftRows+MixColumns (fused), ARK
    for (int r = 1; r <= 9; ++r) {
        sub_group<0>(st, w0g, b0g, w1tg);
        sub_group<2>(st, w0g, b0g, w1tg);

        // ShiftRows folded into MixColumns' source indices:
        // shifted[i][j] = sb[(i+j)&3][j];  mix rolls along j (axis 2)
        #pragma unroll
        for (int k = 0; k < 8; ++k) {
            float ns[4][4];
            #pragma unroll
            for (int i = 0; i < 4; ++i) {
                #pragma unroll
                for (int j = 0; j < 4; ++j) {
                    float s = st[(i + j) & 3][j][k]
                            + st[(i + j + 1) & 3][(j + 1) & 3][k]
                            + st[(i + j + 2) & 3][(j + 2) & 3][k];
                    ns[i][j] = mixg(s);
                }
            }
            #pragma unroll
            for (int i = 0; i < 4; ++i)
                #pragma unroll
                for (int j = 0; j < 4; ++j) st[i][j][k] = ns[i][j];
        }

        // ARK round r (key terms via uniform scalar loads)
        const float* __restrict__ t0p = t0g + r * 128;
        const float* __restrict__ t1p = t1g + r * 128;
        #pragma unroll
        for (int i = 0; i < 4; ++i) {
            #pragma unroll
            for (int j = 0; j < 4; ++j) {
                #pragma unroll
                for (int k = 0; k < 8; ++k) {
                    float c0 = fmaf(w00, st[i][j][k], t0p[i * 32 + j * 8 + k]);
                    float c1 = fmaf(w10, st[i][j][k], t1p[i * 32 + j * 8 + k]);
                    st[i][j][k] = fmaxf(c0, 0.f) + fmaxf(c1, 0.f);
                }
            }
        }
    }

    // Final round: SubBytes, then ShiftRows + ARK(rk[10]) folded into the store
    sub_group<0>(st, w0g, b0g, w1tg);
    sub_group<2>(st, w0g, b0g, w1tg);
    const float* __restrict__ t0p = t0g + 10 * 128;
    const float* __restrict__ t1p = t1g + 10 * 128;
    #pragma unroll
    for (int j = 0; j < 4; ++j) {
        #pragma unroll
        for (int i = 0; i < 4; ++i) {
            float v[8];
            #pragma unroll
            for (int k = 0; k < 8; ++k) {
                float x = st[(i + j) & 3][j][k];   // ShiftRows
                float c0 = fmaf(w00, x, t0p[i * 32 + j * 8 + k]);
                float c1 = fmaf(w10, x, t1p[i * 32 + j * 8 + k]);
                v[k] = fmaxf(c0, 0.f) + fmaxf(c1, 0.f);
            }
            float4 oa = {v[0], v[1], v[2], v[3]};
            float4 oc = {v[4], v[5], v[6], v[7]};
            *(float4*)(op + j * 32 + i * 8) = oa;
            *(float4*)(op + j * 32 + i * 8 + 4) = oc;
        }
    }
}

extern "C" void kernel_launch(void* const* d_in, const int* in_sizes, int n_in,
                              void* d_out, int out_size, void* d_ws, size_t ws_size,
                              hipStream_t stream) {
    const float* st_in = (const float*)d_in[0];
    const float* rk    = (const float*)d_in[1];
    const float* xw    = (const float*)d_in[2];
    const float* xb    = (const float*)d_in[3];
    const float* w0    = (const float*)d_in[4];
    const float* b0    = (const float*)d_in[5];
    const float* w1    = (const float*)d_in[6];
    float* out = (float*)d_out;
    float* ws  = (float*)d_ws;
    const int B = in_sizes[0] / 128;

    prep_kernel<<<6, 256, 0, stream>>>(rk, xw, xb, w1, ws);
    neural_aes_kernel<<<(B + 255) / 256, 256, 0, stream>>>(st_in, xw, w0, b0, ws, out, B);
}

// Round 6
// 393.636 us; speedup vs baseline: 1.1329x; 1.1329x over previous
//
#include <hip/hip_runtime.h>

#define NH 32   // S-box hidden width

// d_ws float layout: [0,256) = w1t (w1 transposed, [h][k]);
//                    [256,1664)  = t0 = w01*rk + xb0  ([11][128]);
//                    [1664,3072) = t1 = w11*rk + xb1  ([11][128]).
#define WS_W1T 0
#define WS_T0  256
#define WS_T1  1664

__global__ __launch_bounds__(256) void prep_kernel(
    const float* __restrict__ rk,   // [11*128]
    const float* __restrict__ xw,   // [4]
    const float* __restrict__ xb,   // [2]
    const float* __restrict__ w1,   // [8][32]
    float* __restrict__ ws)
{
    const int idx = blockIdx.x * 256 + threadIdx.x;
    const float w01 = xw[1], w11 = xw[3], xb0 = xb[0], xb1 = xb[1];
    if (idx < NH * 8) {
        int h = idx >> 3, k = idx & 7;
        ws[WS_W1T + idx] = w1[k * NH + h];
    }
    if (idx < 11 * 128) {
        float kv = rk[idx];
        ws[WS_T0 + idx] = fmaf(w01, kv, xb0);
        ws[WS_T1 + idx] = fmaf(w11, kv, xb1);
    }
}

// XOR-of-3 parity gadget: relu(s) - 2relu(s-1) + 2relu(s-2) - 2relu(s-3)
__device__ __forceinline__ float mixg(float s) {
    float t0 = fmaxf(s, 0.f);
    float t1 = fmaxf(s - 1.f, 0.f);
    float t2 = fmaxf(s - 2.f, 0.f);
    float t3 = fmaxf(s - 3.f, 0.f);
    return t0 - 2.f * (t1 - t2 + t3);
}

// SubBytes on this lane's 4 bytes (j=0..3, contract over k). Weights via
// wave-uniform indices -> scalar loads into SGPRs (verified R4: SGPR=112).
__device__ __forceinline__ void sub_bytes4(const float (&y)[4][8], float (&acc)[4][8],
                                           const float* __restrict__ w0g,
                                           const float* __restrict__ b0g,
                                           const float* __restrict__ w1tg)
{
    #pragma unroll
    for (int j = 0; j < 4; ++j)
        #pragma unroll
        for (int k = 0; k < 8; ++k) acc[j][k] = 0.f;

    #pragma unroll 2
    for (int h = 0; h < NH; ++h) {
        const float* __restrict__ wr = w0g + h * 8;   // uniform -> SGPR
        const float* __restrict__ vr = w1tg + h * 8;  // uniform -> SGPR
        const float bb = b0g[h];                      // uniform -> SGPR
        #pragma unroll
        for (int j = 0; j < 4; ++j) {
            float hv = bb;
            #pragma unroll
            for (int k = 0; k < 8; ++k) hv = fmaf(wr[k], y[j][k], hv);
            hv = fmaxf(hv, 0.f);
            #pragma unroll
            for (int k = 0; k < 8; ++k) acc[j][k] = fmaf(vr[k], hv, acc[j][k]);
        }
    }
}

// ShiftRows: sh[i][j] = sb[(i+j)&3][j] — within reg j, dst lane i pulls from
// quad-lane (i+j)&3. ds_swizzle QDMode, bit-exact. j=0 is identity.
#define SWZ(x, pat) __int_as_float(__builtin_amdgcn_ds_swizzle(__float_as_int(x), pat))

__global__ __launch_bounds__(256, 4) void neural_aes_kernel(
    const float* __restrict__ st_in,   // [B,128]
    const float* __restrict__ xw,      // [2,2]
    const float* __restrict__ w0g,     // [32,8]
    const float* __restrict__ b0g,     // [32]
    const float* __restrict__ wsg,     // w1t + t0 + t1 (prepped)
    float* __restrict__ out, int B)
{
    const float w00 = xw[0], w10 = xw[2];
    const float* __restrict__ w1tg = wsg + WS_W1T;
    const float* __restrict__ t0g  = wsg + WS_T0;
    const float* __restrict__ t1g  = wsg + WS_T1;

    const int t = blockIdx.x * 256 + threadIdx.x;
    const int b = t >> 2;        // AES block index (4 lanes per block)
    const int i = t & 3;         // owned row index; quad lanes = one block
    if (b >= B) return;
    const float* __restrict__ inp = st_in + (size_t)b * 128 + i * 8;
    float* __restrict__ op = out + (size_t)b * 128 + i * 8;

    // y[j][k] = st[i][j][k] = mem[j*32 + i*8 + k]
    float y[4][8];
    float acc[4][8];
    #pragma unroll
    for (int j = 0; j < 4; ++j) {
        float4 a = *(const float4*)(inp + j * 32);
        float4 c = *(const float4*)(inp + j * 32 + 4);
        y[j][0] = a.x; y[j][1] = a.y; y[j][2] = a.z; y[j][3] = a.w;
        y[j][4] = c.x; y[j][5] = c.y; y[j][6] = c.z; y[j][7] = c.w;
    }

    // Initial ARK (round key 0): key term index = i*32 + j*8 + k
    #pragma unroll
    for (int j = 0; j < 4; ++j) {
        float4 q0 = *(const float4*)(t0g + i * 32 + j * 8);
        float4 q1 = *(const float4*)(t0g + i * 32 + j * 8 + 4);
        float4 q2 = *(const float4*)(t1g + i * 32 + j * 8);
        float4 q3 = *(const float4*)(t1g + i * 32 + j * 8 + 4);
        float ta[8] = {q0.x, q0.y, q0.z, q0.w, q1.x, q1.y, q1.z, q1.w};
        float tb[8] = {q2.x, q2.y, q2.z, q2.w, q3.x, q3.y, q3.z, q3.w};
        #pragma unroll
        for (int k = 0; k < 8; ++k) {
            float c0 = fmaf(w00, y[j][k], ta[k]);
            float c1 = fmaf(w10, y[j][k], tb[k]);
            y[j][k] = fmaxf(c0, 0.f) + fmaxf(c1, 0.f);
        }
    }

    // Rounds 1..9: SubBytes, ShiftRows (swizzle), MixColumns, ARK
    for (int r = 1; r <= 9; ++r) {
        sub_bytes4(y, acc, w0g, b0g, w1tg);

        // ShiftRows: y[j] = quad-rotate_j(acc[j])
        #pragma unroll
        for (int k = 0; k < 8; ++k) {
            y[0][k] = acc[0][k];
            y[1][k] = SWZ(acc[1][k], 0x8039);  // src = (i+1)&3
            y[2][k] = SWZ(acc[2][k], 0x804E);  // src = (i+2)&3
            y[3][k] = SWZ(acc[3][k], 0x8093);  // src = (i+3)&3
        }

        // MixColumns: out[j] = g(sh[j] + sh[(j+1)&3] + sh[(j+2)&3]) — lane-local
        #pragma unroll
        for (int k = 0; k < 8; ++k) {
            float m0 = mixg(y[0][k] + y[1][k] + y[2][k]);
            float m1 = mixg(y[1][k] + y[2][k] + y[3][k]);
            float m2 = mixg(y[2][k] + y[3][k] + y[0][k]);
            float m3 = mixg(y[3][k] + y[0][k] + y[1][k]);
            y[0][k] = m0; y[1][k] = m1; y[2][k] = m2; y[3][k] = m3;
        }

        // ARK round r
        #pragma unroll
        for (int j = 0; j < 4; ++j) {
            float4 q0 = *(const float4*)(t0g + r * 128 + i * 32 + j * 8);
            float4 q1 = *(const float4*)(t0g + r * 128 + i * 32 + j * 8 + 4);
            float4 q2 = *(const float4*)(t1g + r * 128 + i * 32 + j * 8);
            float4 q3 = *(const float4*)(t1g + r * 128 + i * 32 + j * 8 + 4);
            float ta[8] = {q0.x, q0.y, q0.z, q0.w, q1.x, q1.y, q1.z, q1.w};
            float tb[8] = {q2.x, q2.y, q2.z, q2.w, q3.x, q3.y, q3.z, q3.w};
            #pragma unroll
            for (int k = 0; k < 8; ++k) {
                float c0 = fmaf(w00, y[j][k], ta[k]);
                float c1 = fmaf(w10, y[j][k], tb[k]);
                y[j][k] = fmaxf(c0, 0.f) + fmaxf(c1, 0.f);
            }
        }
    }

    // Final round: SubBytes, ShiftRows, ARK(rk[10]) — no MixColumns
    sub_bytes4(y, acc, w0g, b0g, w1tg);
    #pragma unroll
    for (int k = 0; k < 8; ++k) {
        y[0][k] = acc[0][k];
        y[1][k] = SWZ(acc[1][k], 0x8039);
        y[2][k] = SWZ(acc[2][k], 0x804E);
        y[3][k] = SWZ(acc[3][k], 0x8093);
    }
    #pragma unroll
    for (int j = 0; j < 4; ++j) {
        float4 q0 = *(const float4*)(t0g + 10 * 128 + i * 32 + j * 8);
        float4 q1 = *(const float4*)(t0g + 10 * 128 + i * 32 + j * 8 + 4);
        float4 q2 = *(const float4*)(t1g + 10 * 128 + i * 32 + j * 8);
        float4 q3 = *(const float4*)(t1g + 10 * 128 + i * 32 + j * 8 + 4);
        float ta[8] = {q0.x, q0.y, q0.z, q0.w, q1.x, q1.y, q1.z, q1.w};
        float tb[8] = {q2.x, q2.y, q2.z, q2.w, q3.x, q3.y, q3.z, q3.w};
        float v[8];
        #pragma unroll
        for (int k = 0; k < 8; ++k) {
            float c0 = fmaf(w00, y[j][k], ta[k]);
            float c1 = fmaf(w10, y[j][k], tb[k]);
            v[k] = fmaxf(c0, 0.f) + fmaxf(c1, 0.f);
        }
        float4 oa = {v[0], v[1], v[2], v[3]};
        float4 oc = {v[4], v[5], v[6], v[7]};
        *(float4*)(op + j * 32) = oa;
        *(float4*)(op + j * 32 + 4) = oc;
    }
}

extern "C" void kernel_launch(void* const* d_in, const int* in_sizes, int n_in,
                              void* d_out, int out_size, void* d_ws, size_t ws_size,
                              hipStream_t stream) {
    const float* st_in = (const float*)d_in[0];
    const float* rk    = (const float*)d_in[1];
    const float* xw    = (const float*)d_in[2];
    const float* xb    = (const float*)d_in[3];
    const float* w0    = (const float*)d_in[4];
    const float* b0    = (const float*)d_in[5];
    const float* w1    = (const float*)d_in[6];
    float* out = (float*)d_out;
    float* ws  = (float*)d_ws;
    const int B = in_sizes[0] / 128;

    prep_kernel<<<6, 256, 0, stream>>>(rk, xw, xb, w1, ws);
    const int threads = B * 4;   // 4 lanes per AES block
    neural_aes_kernel<<<(threads + 255) / 256, 256, 0, stream>>>(st_in, xw, w0, b0, ws, out, B);
}

// Round 7
// 363.058 us; speedup vs baseline: 1.2284x; 1.0842x over previous
//
#include <hip/hip_runtime.h>

#define NH 32   // S-box hidden width

// d_ws float layout: [0,256) = w1t (w1 transposed, [h][k])
#define WS_W1T 0

__global__ __launch_bounds__(256) void prep_kernel(
    const float* __restrict__ w1,   // [8][32]
    float* __restrict__ ws)
{
    const int idx = threadIdx.x;          // one block of 256
    if (idx < NH * 8) {
        int h = idx >> 3, k = idx & 7;
        ws[WS_W1T + idx] = w1[k * NH + h];
    }
}

// quad-lane swizzles (verified in R6): dst q reads src (q+1)&3 / (q+2)&3
#define SWZ(x, pat) __int_as_float(__builtin_amdgcn_ds_swizzle(__float_as_int(x), pat))
#define BPERM(a, x) __int_as_float(__builtin_amdgcn_ds_bpermute((a), __float_as_int(x)))

// mixg(s) = relu(s) - 2relu(s-1) + 2relu(s-2) - 2relu(s-3)
//         = 1 - |1 - |relu(s) - 2||   (identical; abs = free VOP3 src modifier)
__device__ __forceinline__ float mixg(float s) {
    float r = fmaxf(s, 0.f);
    float a = r - 2.f;
    float w = 1.f - __builtin_fabsf(a);
    return 1.f - __builtin_fabsf(w);
}

__global__ __launch_bounds__(256, 4) void neural_aes_kernel(
    const float* __restrict__ st_in,   // [B,128]
    const float* __restrict__ rk,      // [11,1,4,4,8]
    const float* __restrict__ xw,      // [2,2]  (xw[0] = c; structure [[c,-c],[-c,c]], xb=0)
    const float* __restrict__ w0g,     // [32,8]
    const float* __restrict__ b0g,     // [32]
    const float* __restrict__ w1tg,    // [32,8] transposed w1 (prepped)
    float* __restrict__ out, int B)
{
    const float c = xw[0];

    const int t = blockIdx.x * 256 + threadIdx.x;
    const int b = t >> 4;              // AES block (16 lanes per block)
    const int l16 = t & 15;
    const int i = l16 >> 2;            // axis-1 index (quad id within group)
    const int j = l16 & 3;             // axis-2 index (lane within quad)
    if (b >= B) return;

    // ShiftRows: dst(i,j) <- src((i+j)&3, j); cross-quad -> bpermute, addr once
    const int lane = threadIdx.x & 63;
    const int bpaddr = (((lane & ~15) | (((i + j) & 3) * 4 + j)) << 2);

    // state element addr = b*128 + j*32 + i*8 + k ; rk addr = r*128 + i*32 + j*8 + k
    const float* __restrict__ inp = st_in + (size_t)b * 128 + j * 32 + i * 8;
    float* __restrict__ op = out + (size_t)b * 128 + j * 32 + i * 8;
    const float* __restrict__ rkl = rk + i * 32 + j * 8;

    float y[8], acc[8];

    // Load + initial ARK: y = c*|x - k0|
    {
        float4 a0 = *(const float4*)(inp);
        float4 a1 = *(const float4*)(inp + 4);
        float4 k0 = *(const float4*)(rkl);
        float4 k1 = *(const float4*)(rkl + 4);
        y[0] = c * __builtin_fabsf(a0.x - k0.x);
        y[1] = c * __builtin_fabsf(a0.y - k0.y);
        y[2] = c * __builtin_fabsf(a0.z - k0.z);
        y[3] = c * __builtin_fabsf(a0.w - k0.w);
        y[4] = c * __builtin_fabsf(a1.x - k1.x);
        y[5] = c * __builtin_fabsf(a1.y - k1.y);
        y[6] = c * __builtin_fabsf(a1.z - k1.z);
        y[7] = c * __builtin_fabsf(a1.w - k1.w);
    }

    for (int r = 1; r <= 10; ++r) {
        // ---- SubBytes (lane-local 8->32->8 MLP; weights via uniform scalar loads)
        #pragma unroll
        for (int k = 0; k < 8; ++k) acc[k] = 0.f;
        #pragma unroll 2
        for (int h = 0; h < NH; ++h) {
            const float* __restrict__ wr = w0g + h * 8;   // uniform -> SGPR
            const float* __restrict__ vr = w1tg + h * 8;  // uniform -> SGPR
            float hv = b0g[h];
            #pragma unroll
            for (int k = 0; k < 8; ++k) hv = fmaf(wr[k], y[k], hv);
            hv = fmaxf(hv, 0.f);
            #pragma unroll
            for (int k = 0; k < 8; ++k) acc[k] = fmaf(vr[k], hv, acc[k]);
        }

        // ---- ShiftRows: pull from lane ((i+j)&3, j)
        #pragma unroll
        for (int k = 0; k < 8; ++k) y[k] = BPERM(bpaddr, acc[k]);

        // ---- MixColumns (skip on final round): neighbors j+1, j+2 via quad swizzle
        if (r < 10) {
            #pragma unroll
            for (int k = 0; k < 8; ++k) {
                float n1 = SWZ(y[k], 0x8039);   // (j+1)&3
                float n2 = SWZ(y[k], 0x804E);   // (j+2)&3
                y[k] = mixg(y[k] + n1 + n2);
            }
        }

        // ---- ARK: y = c*|y - k_r|   (rk tiny -> L1/L2 resident)
        const float* __restrict__ rkr = rkl + r * 128;
        float4 k0 = *(const float4*)(rkr);
        float4 k1 = *(const float4*)(rkr + 4);
        y[0] = c * __builtin_fabsf(y[0] - k0.x);
        y[1] = c * __builtin_fabsf(y[1] - k0.y);
        y[2] = c * __builtin_fabsf(y[2] - k0.z);
        y[3] = c * __builtin_fabsf(y[3] - k0.w);
        y[4] = c * __builtin_fabsf(y[4] - k1.x);
        y[5] = c * __builtin_fabsf(y[5] - k1.y);
        y[6] = c * __builtin_fabsf(y[6] - k1.z);
        y[7] = c * __builtin_fabsf(y[7] - k1.w);
    }

    float4 oa = {y[0], y[1], y[2], y[3]};
    float4 oc = {y[4], y[5], y[6], y[7]};
    *(float4*)(op) = oa;
    *(float4*)(op + 4) = oc;
}

extern "C" void kernel_launch(void* const* d_in, const int* in_sizes, int n_in,
                              void* d_out, int out_size, void* d_ws, size_t ws_size,
                              hipStream_t stream) {
    const float* st_in = (const float*)d_in[0];
    const float* rk    = (const float*)d_in[1];
    const float* xw    = (const float*)d_in[2];
    const float* w0    = (const float*)d_in[4];
    const float* b0    = (const float*)d_in[5];
    const float* w1    = (const float*)d_in[6];
    float* out = (float*)d_out;
    float* ws  = (float*)d_ws;
    const int B = in_sizes[0] / 128;

    prep_kernel<<<1, 256, 0, stream>>>(w1, ws);
    const long long threads = (long long)B * 16;   // 16 lanes per AES block
    neural_aes_kernel<<<(int)((threads + 255) / 256), 256, 0, stream>>>(
        st_in, rk, xw, w0, b0, ws, out, B);
}

// Round 8
// 355.836 us; speedup vs baseline: 1.2533x; 1.0203x over previous
//
#include <hip/hip_runtime.h>

#define NH 32   // S-box hidden width

typedef float v2f __attribute__((ext_vector_type(2)));

// d_ws float layout: [0,256) = w1t (w1 transposed, [h][k])
#define WS_W1T 0

__global__ __launch_bounds__(256) void prep_kernel(
    const float* __restrict__ w1,   // [8][32]
    float* __restrict__ ws)
{
    const int idx = threadIdx.x;          // one block of 256
    if (idx < NH * 8) {
        int h = idx >> 3, k = idx & 7;
        ws[WS_W1T + idx] = w1[k * NH + h];
    }
}

// quad-lane swizzles (verified R6/R7): dst q reads src (q+1)&3 / (q+2)&3
#define SWZ(x, pat) __int_as_float(__builtin_amdgcn_ds_swizzle(__float_as_int(x), pat))
#define BPERM(a, x) __int_as_float(__builtin_amdgcn_ds_bpermute((a), __float_as_int(x)))

// mixg(s) = relu(s) - 2relu(s-1) + 2relu(s-2) - 2relu(s-3)
//         = 1 - |1 - |relu(s) - 2||  (identical; |x| = free VOP3 src modifier)
__device__ __forceinline__ float mixg(float s) {
    float r = fmaxf(s, 0.f);
    float a = r - 2.f;
    float w = 1.f - __builtin_fabsf(a);
    return 1.f - __builtin_fabsf(w);
}

__global__ __launch_bounds__(256, 4) void neural_aes_kernel(
    const float* __restrict__ st_in,   // [B,128]
    const float* __restrict__ rk,      // [11,1,4,4,8]
    const float* __restrict__ xw,      // [2,2]  ([[c,-c],[-c,c]], xb=0 by construction)
    const float* __restrict__ w0g,     // [32,8]
    const float* __restrict__ b0g,     // [32]
    const float* __restrict__ w1tg,    // [32,8] transposed w1 (prepped)
    float* __restrict__ out, int B)
{
    const float c = xw[0];

    const int t = blockIdx.x * 256 + threadIdx.x;
    const int b = t >> 4;              // AES block (16 lanes per block)
    const int l16 = t & 15;
    const int i = l16 >> 2;            // axis-1 index (quad id within group)
    const int j = l16 & 3;             // axis-2 index (lane within quad)
    if (b >= B) return;

    // ShiftRows: dst(i,j) <- src((i+j)&3, j); cross-quad -> bpermute (addr once)
    const int lane = threadIdx.x & 63;
    const int bpaddr = (((lane & ~15) | (((i + j) & 3) * 4 + j)) << 2);

    // state addr = b*128 + j*32 + i*8 + k ; rk addr = r*128 + i*32 + j*8 + k
    const float* __restrict__ inp = st_in + (size_t)b * 128 + j * 32 + i * 8;
    float* __restrict__ op = out + (size_t)b * 128 + j * 32 + i * 8;
    const float* __restrict__ rkl = rk + i * 32 + j * 8;

    float y[8];

    // Load + initial ARK: y = c*|x - k0|
    {
        float4 a0 = *(const float4*)(inp);
        float4 a1 = *(const float4*)(inp + 4);
        float4 k0 = *(const float4*)(rkl);
        float4 k1 = *(const float4*)(rkl + 4);
        y[0] = c * __builtin_fabsf(a0.x - k0.x);
        y[1] = c * __builtin_fabsf(a0.y - k0.y);
        y[2] = c * __builtin_fabsf(a0.z - k0.z);
        y[3] = c * __builtin_fabsf(a0.w - k0.w);
        y[4] = c * __builtin_fabsf(a1.x - k1.x);
        y[5] = c * __builtin_fabsf(a1.y - k1.y);
        y[6] = c * __builtin_fabsf(a1.z - k1.z);
        y[7] = c * __builtin_fabsf(a1.w - k1.w);
    }

    for (int r = 1; r <= 10; ++r) {
        // ---- SubBytes (lane-local 8->32->8 MLP), packed-fp32 (v_pk_fma_f32)
        v2f y2[4], acc2[4];
        #pragma unroll
        for (int p = 0; p < 4; ++p) {
            y2[p] = (v2f){y[2 * p], y[2 * p + 1]};
            acc2[p] = (v2f)(0.f);
        }
        #pragma unroll 2
        for (int h = 0; h < NH; ++h) {
            const v2f* __restrict__ wr2 = (const v2f*)(w0g + h * 8);   // uniform -> SGPR
            const v2f* __restrict__ vr2 = (const v2f*)(w1tg + h * 8);  // uniform -> SGPR
            v2f hp = (v2f){b0g[h], 0.f};
            hp = wr2[0] * y2[0] + hp;   // fmuladd -> v_pk_fma_f32
            hp = wr2[1] * y2[1] + hp;
            hp = wr2[2] * y2[2] + hp;
            hp = wr2[3] * y2[3] + hp;
            float hv = fmaxf(hp.x + hp.y, 0.f);
            v2f hv2 = (v2f){hv, hv};    // splat folds into op_sel
            acc2[0] = vr2[0] * hv2 + acc2[0];
            acc2[1] = vr2[1] * hv2 + acc2[1];
            acc2[2] = vr2[2] * hv2 + acc2[2];
            acc2[3] = vr2[3] * hv2 + acc2[3];
        }

        // ---- ShiftRows: pull from lane ((i+j)&3, j)
        #pragma unroll
        for (int p = 0; p < 4; ++p) {
            y[2 * p]     = BPERM(bpaddr, acc2[p].x);
            y[2 * p + 1] = BPERM(bpaddr, acc2[p].y);
        }

        // ---- MixColumns (skip final round): neighbors j+1, j+2 via quad swizzle
        if (r < 10) {
            #pragma unroll
            for (int k = 0; k < 8; ++k) {
                float n1 = SWZ(y[k], 0x8039);   // (j+1)&3
                float n2 = SWZ(y[k], 0x804E);   // (j+2)&3
                y[k] = mixg(y[k] + n1 + n2);
            }
        }

        // ---- ARK: y = c*|y - k_r|   (rk tiny -> L1/L2 resident)
        const float* __restrict__ rkr = rkl + r * 128;
        float4 k0 = *(const float4*)(rkr);
        float4 k1 = *(const float4*)(rkr + 4);
        y[0] = c * __builtin_fabsf(y[0] - k0.x);
        y[1] = c * __builtin_fabsf(y[1] - k0.y);
        y[2] = c * __builtin_fabsf(y[2] - k0.z);
        y[3] = c * __builtin_fabsf(y[3] - k0.w);
        y[4] = c * __builtin_fabsf(y[4] - k1.x);
        y[5] = c * __builtin_fabsf(y[5] - k1.y);
        y[6] = c * __builtin_fabsf(y[6] - k1.z);
        y[7] = c * __builtin_fabsf(y[7] - k1.w);
    }

    float4 oa = {y[0], y[1], y[2], y[3]};
    float4 oc = {y[4], y[5], y[6], y[7]};
    *(float4*)(op) = oa;
    *(float4*)(op + 4) = oc;
}

extern "C" void kernel_launch(void* const* d_in, const int* in_sizes, int n_in,
                              void* d_out, int out_size, void* d_ws, size_t ws_size,
                              hipStream_t stream) {
    const float* st_in = (const float*)d_in[0];
    const float* rk    = (const float*)d_in[1];
    const float* xw    = (const float*)d_in[2];
    const float* w0    = (const float*)d_in[4];
    const float* b0    = (const float*)d_in[5];
    const float* w1    = (const float*)d_in[6];
    float* out = (float*)d_out;
    float* ws  = (float*)d_ws;
    const int B = in_sizes[0] / 128;

    prep_kernel<<<1, 256, 0, stream>>>(w1, ws);
    const long long threads = (long long)B * 16;   // 16 lanes per AES block
    neural_aes_kernel<<<(int)((threads + 255) / 256), 256, 0, stream>>>(
        st_in, rk, xw, w0, b0, ws, out, B);
}